// Round 1
// baseline (228.774 us; speedup 1.0000x reference)
//
#include <hip/hip_runtime.h>
#include <cstdint>

#define N_NODES 50000
#define N_EDGES 800000
#define C 64
#define SLOTS 64                    // fixed CSR slots/node (deg~Bin: mean 16, max ~40)
#define B_N 120                     // nodes per coarse bucket
#define NB 417                      // ceil(N/B_N)
#define PCAP 2560                   // staging cap/bucket (mean 1918, ~14 sigma)
#define STG_BLOCKS 126
#define STG_CHUNK 6350              // 126*6350 >= E

typedef __attribute__((ext_vector_type(8))) short bf16x8;   // 8 bf16 in 4 VGPRs
typedef __attribute__((ext_vector_type(4))) float f32x4;

// ---------------- workspace layout (word units) ----------------
// Round-12: prop kernels fused into the GEMMs (prop->GEMM handoff via LDS).
// Phb/Prhb never hit global anymore; Pxb still materialized (re-read by gemm_h).
static constexpr size_t OFF_GCUR = 0;                                // 512 ints
static constexpr size_t OFF_DINV = 512;                              // 50176 fl
static constexpr size_t OFF_CNT  = 50688;                            // 50176 ints
static constexpr size_t OFF_BZR  = 100864;                           // 16384 fl
static constexpr size_t OFF_BH   = 117248;                           // 8192 fl
static constexpr size_t OFF_CSR  = 125440;                           // N*64 uints = 3.2M
static constexpr size_t OFF_XH   = OFF_CSR + (size_t)N_NODES * 64;   // N*C uints
static constexpr size_t OFF_XB   = OFF_XH + (size_t)N_NODES * C;     // N*C ushort
static constexpr size_t OFF_HB   = OFF_XB + (size_t)N_NODES * C / 2;
static constexpr size_t OFF_PXB  = OFF_HB + (size_t)N_NODES * C / 2;
static constexpr size_t OFF_PHB  = OFF_PXB + (size_t)N_NODES * C / 2; // dead (stg alias only)
static constexpr size_t OFF_RHB  = OFF_PHB + (size_t)N_NODES * C / 2;
static constexpr size_t OFF_RHD  = OFF_RHB + (size_t)N_NODES * C / 2;
// stg aliases PXB..: needs 2*NB*PCAP = 2,135,040 words < 4*1.6M available there.
static constexpr size_t OFF_STG  = OFF_PXB;          // uint2; byte off %8==0
// end = OFF_RHD + N*C/2 = 16,125,440 words = 64.5 MB (<= 67.4 MB proven in r0)

__device__ __forceinline__ short f2bf(float f) {             // RNE fp32 -> bf16
    unsigned u = __float_as_uint(f);
    u += 0x7fffu + ((u >> 16) & 1u);
    return (short)(u >> 16);
}
__device__ __forceinline__ float bf_lo(unsigned v) { return __uint_as_float(v << 16); }
__device__ __forceinline__ float bf_hi(unsigned v) { return __uint_as_float(v & 0xffff0000u); }
__device__ __forceinline__ float bfu(unsigned short v) { return __uint_as_float((unsigned)v << 16); }
__device__ __forceinline__ float fast_sigmoid(float v) { return 1.f / (1.f + __expf(-v)); }
__device__ __forceinline__ float fast_tanh(float v) { return 1.f - 2.f / (__expf(2.f * v) + 1.f); }

// ======================= K1: zero gcur + weight pack =======================
__global__ __launch_bounds__(256) void zero_pack_kernel(
        int* __restrict__ gcur,
        const float* __restrict__ Wz, const float* __restrict__ Wr,
        const float* __restrict__ Wh,
        short* __restrict__ Bzr, short* __restrict__ Bh) {
    if (blockIdx.x == 24) {
        gcur[threadIdx.x] = 0;
        gcur[256 + threadIdx.x] = 0;
        return;
    }
    int gid = blockIdx.x * 256 + threadIdx.x;           // < 6144
    if (gid < 4096) {                                   // zr: 64 (kt,ct) x 64 lanes
        int ktct = gid >> 6, lane = gid & 63;
        int kt = ktct >> 3, ct = ktct & 7;
        int colg = ct * 16 + (lane & 15);
        int k0 = kt * 32 + (lane >> 4) * 8;
        const float* W = (colg < 64) ? Wz : Wr;
        int c = colg & 63;
        short v[8];
        #pragma unroll
        for (int j = 0; j < 8; ++j) {
            int k = k0 + j;
            v[j] = f2bf(W[(k >> 7) * (128 * 64) + (k & 127) * 64 + c]);
        }
        *(bf16x8*)(Bzr + (size_t)ktct * 512 + lane * 8) = *(bf16x8*)v;
    } else {                                            // h: 32 (kt,ct) x 64 lanes
        int idx = gid - 4096;
        int ktct = idx >> 6, lane = idx & 63;
        int kt = ktct >> 2, ct = ktct & 3;
        int colg = ct * 16 + (lane & 15);
        int k0 = kt * 32 + (lane >> 4) * 8;
        short v[8];
        #pragma unroll
        for (int j = 0; j < 8; ++j) {
            int k = k0 + j;
            v[j] = f2bf(Wh[(k >> 7) * (128 * 64) + (k & 127) * 64 + colg]);
        }
        *(bf16x8*)(Bh + (size_t)ktct * 512 + lane * 8) = *(bf16x8*)v;
    }
}

// ======================= K2: stage edges into coarse buckets =======================
__global__ __launch_bounds__(512) void stage_kernel(
        const int* __restrict__ row, const int* __restrict__ col,
        const float* __restrict__ w,
        int* __restrict__ gcur, uint2* __restrict__ stg) {
    __shared__ int lcnt[NB];
    __shared__ int lbase[NB];
    int tid = threadIdx.x;
    int e0 = blockIdx.x * STG_CHUNK;
    int e1 = min(e0 + STG_CHUNK, N_EDGES);
    for (int i = tid; i < NB; i += 512) lcnt[i] = 0;
    __syncthreads();
    for (int e = e0 + tid; e < e1; e += 512)
        atomicAdd(&lcnt[row[e] / B_N], 1);
    __syncthreads();
    for (int i = tid; i < NB; i += 512) {
        int c = lcnt[i];
        lbase[i] = c ? atomicAdd(&gcur[i], c) : 0;
        lcnt[i] = 0;
    }
    __syncthreads();
    for (int e = e0 + tid; e < e1; e += 512) {
        int r = row[e];
        int b = r / B_N;
        int off = atomicAdd(&lcnt[b], 1);
        int pos = lbase[b] + off;
        unsigned cw = ((unsigned)col[e] << 16) | (unsigned short)f2bf(w[e]);
        if (pos < PCAP)
            stg[(size_t)b * PCAP + pos] = make_uint2((unsigned)(r - b * B_N), cw);
    }
}

// ======================= K3: bucket-sort -> slot-CSR + cnt/dinv + feature pack =====
__global__ __launch_bounds__(256) void sort_kernel(
        const int* __restrict__ gcur, const uint2* __restrict__ stg,
        const float* __restrict__ x, const float* __restrict__ h,
        unsigned* __restrict__ csr, int* __restrict__ cnt, float* __restrict__ dinv,
        unsigned* __restrict__ xh,
        unsigned short* __restrict__ xb, unsigned short* __restrict__ hb) {
    __shared__ int lcnt[B_N];
    __shared__ int lbase[B_N];
    __shared__ float ldeg[B_N];
    __shared__ float ldv[B_N];
    __shared__ int scanb[128];
    __shared__ unsigned lbuf[PCAP];
    __shared__ unsigned char lnode[PCAP];
    int b = blockIdx.x, tid = threadIdx.x;
    int n0 = b * B_N;
    int m = min(gcur[b], PCAP);
    for (int i = tid; i < B_N; i += 256) { lcnt[i] = 0; ldeg[i] = 0.f; }
    __syncthreads();
    const uint2* s = stg + (size_t)b * PCAP;
    for (int i = tid; i < m; i += 256) {             // pass 1: per-node count + deg
        uint2 e = s[i];
        atomicAdd(&lcnt[e.x], 1);
        atomicAdd(&ldeg[e.x], bf_lo(e.y));
    }
    __syncthreads();
    if (tid < 128) scanb[tid] = (tid < B_N) ? lcnt[tid] : 0;   // inclusive scan (128)
    __syncthreads();
    for (int d = 1; d < 128; d <<= 1) {
        int v = 0;
        if (tid < 128 && tid >= d) v = scanb[tid - d];
        __syncthreads();
        if (tid < 128) scanb[tid] += v;
        __syncthreads();
    }
    if (tid < B_N) { lbase[tid] = scanb[tid] - lcnt[tid]; lcnt[tid] = 0; }
    __syncthreads();
    for (int i = tid; i < m; i += 256) {             // pass 2: LDS scatter (sorted)
        uint2 e = s[i];
        int off = atomicAdd(&lcnt[e.x], 1);
        int p = lbase[e.x] + off;
        lbuf[p] = e.y;
        lnode[p] = (unsigned char)e.x;
    }
    __syncthreads();
    for (int i = tid; i < m; i += 256) {             // stream out, coalesced per node
        int nl = lnode[i];
        int pos = i - lbase[nl];
        csr[(size_t)(n0 + nl) * SLOTS + pos] = lbuf[i];
    }
    if (tid < B_N) {                                  // cnt + dinv
        int node = n0 + tid;
        if (node < N_NODES) {
            cnt[node] = lcnt[tid];
            float d = ldeg[tid];
            float dv = (d > 0.f) ? rsqrtf(d) : 0.f;
            dinv[node] = dv;
            ldv[tid] = dv;
        } else ldv[tid] = 0.f;
    }
    __syncthreads();
    for (int i = tid; i < B_N * 16; i += 256) {       // feature pack (float4 groups)
        int g = n0 * 16 + i;
        if (g >= N_NODES * 16) continue;
        float dv = ldv[i >> 4];
        float4 xv = ((const float4*)x)[g];
        float4 hv = ((const float4*)h)[g];
        uint4 o;
        o.x = ((unsigned)(unsigned short)f2bf(hv.x * dv) << 16) | (unsigned short)f2bf(xv.x * dv);
        o.y = ((unsigned)(unsigned short)f2bf(hv.y * dv) << 16) | (unsigned short)f2bf(xv.y * dv);
        o.z = ((unsigned)(unsigned short)f2bf(hv.z * dv) << 16) | (unsigned short)f2bf(xv.z * dv);
        o.w = ((unsigned)(unsigned short)f2bf(hv.w * dv) << 16) | (unsigned short)f2bf(xv.w * dv);
        ((uint4*)xh)[g] = o;
        ((short4*)xb)[g] = make_short4(f2bf(xv.x), f2bf(xv.y), f2bf(xv.z), f2bf(xv.w));
        ((short4*)hb)[g] = make_short4(f2bf(hv.x), f2bf(hv.y), f2bf(hv.z), f2bf(hv.w));
    }
}

// ======================= K4: fused prop2 + zr-GEMM =======================
// Block = 256 thr = 4 waves = 16 nodes. Phase A: wave w gathers nodes w*4..w*4+3
// (lane = channel, unroll-4 edge loop), P-rows land in padded LDS (stride 72
// ushorts = 144 B -> 16-lane b128 reads hit 8 bank groups, conflict-free) and
// Pxb also goes to global (re-read by gemm_h). Phase B: wave w computes the
// 16x32 column tile ct = {2w, 2w+1} of the 16x128 zr output.
__global__ __launch_bounds__(256) void prop_gemm_zr_kernel(
        const int* __restrict__ cnt, const unsigned* __restrict__ csr,
        const float* __restrict__ dinv, const unsigned* __restrict__ xh,
        const unsigned short* __restrict__ xb, const unsigned short* __restrict__ hb,
        const short* __restrict__ Bzr,
        const float* __restrict__ bz, const float* __restrict__ br,
        unsigned short* __restrict__ Pxb,
        float* __restrict__ z, unsigned short* __restrict__ rhb,
        unsigned short* __restrict__ rhd) {
    __shared__ __align__(16) unsigned short lpx[16][72];
    __shared__ __align__(16) unsigned short lph[16][72];
    int tid = threadIdx.x;
    int wid = tid >> 6, lane = tid & 63;
    int node0 = blockIdx.x * 16;                      // 3125 blocks, exact

    // ---- phase A: gather 4 nodes per wave ----
    #pragma unroll
    for (int i = 0; i < 4; ++i) {
        int nl = wid * 4 + i;
        int n = node0 + nl;
        int m = min(cnt[n], SLOTS);
        const unsigned* s = csr + (size_t)n * SLOTS;
        float ax = 0.f, ah = 0.f;
        int e = 0;
        for (; e + 4 <= m; e += 4) {
            unsigned p0 = s[e], p1 = s[e + 1], p2 = s[e + 2], p3 = s[e + 3];
            unsigned v0 = xh[(p0 >> 16) * C + lane];
            unsigned v1 = xh[(p1 >> 16) * C + lane];
            unsigned v2 = xh[(p2 >> 16) * C + lane];
            unsigned v3 = xh[(p3 >> 16) * C + lane];
            float w0 = bf_lo(p0), w1 = bf_lo(p1), w2 = bf_lo(p2), w3 = bf_lo(p3);
            ax = fmaf(w0, bf_lo(v0), ax);  ah = fmaf(w0, bf_hi(v0), ah);
            ax = fmaf(w1, bf_lo(v1), ax);  ah = fmaf(w1, bf_hi(v1), ah);
            ax = fmaf(w2, bf_lo(v2), ax);  ah = fmaf(w2, bf_hi(v2), ah);
            ax = fmaf(w3, bf_lo(v3), ax);  ah = fmaf(w3, bf_hi(v3), ah);
        }
        for (; e < m; ++e) {
            unsigned p = s[e];
            unsigned v = xh[(p >> 16) * C + lane];
            float wv = bf_lo(p);
            ax = fmaf(wv, bf_lo(v), ax);
            ah = fmaf(wv, bf_hi(v), ah);
        }
        float sc = -dinv[n];
        unsigned short px = (unsigned short)f2bf(sc * ax);
        unsigned short ph = (unsigned short)f2bf(sc * ah);
        lpx[nl][lane] = px;
        lph[nl][lane] = ph;
        Pxb[(size_t)n * C + lane] = px;               // still needed by gemm_h
    }
    __syncthreads();

    // ---- phase B: 16 nodes x 32 cols per wave ----
    int q = lane >> 4;
    int nl = lane & 15;
    f32x4 acc[2];
    acc[0] = (f32x4){0.f, 0.f, 0.f, 0.f};
    acc[1] = (f32x4){0.f, 0.f, 0.f, 0.f};
    const bf16x8* Bp = (const bf16x8*)Bzr;
    #pragma unroll
    for (int kt = 0; kt < 8; ++kt) {
        bf16x8 a;
        if (kt < 4) {
            const unsigned short* src = (kt < 2) ? xb : hb;
            a = *(const bf16x8*)(src + (size_t)(node0 + nl) * C + (kt & 1) * 32 + q * 8);
        } else {
            const unsigned short* src = (kt < 6) ? &lpx[0][0] : &lph[0][0];
            a = *(const bf16x8*)(src + nl * 72 + (kt & 1) * 32 + q * 8);
        }
        #pragma unroll
        for (int c2 = 0; c2 < 2; ++c2) {
            int ct = wid * 2 + c2;
            bf16x8 bfr = Bp[(kt * 8 + ct) * 64 + lane];
            acc[c2] = __builtin_amdgcn_mfma_f32_16x16x32_bf16(a, bfr, acc[c2], 0, 0, 0);
        }
    }

    if (wid < 2) {                                    // z columns (ct 0..3)
        #pragma unroll
        for (int c2 = 0; c2 < 2; ++c2) {
            int colg = (wid * 2 + c2) * 16 + nl;
            float bias = bz[colg];
            #pragma unroll
            for (int r = 0; r < 4; ++r) {
                int node = node0 + q * 4 + r;
                z[(size_t)node * C + colg] = fast_sigmoid(acc[c2][r] + bias);
            }
        }
    } else {                                          // r columns (ct 4..7)
        float dv[4];
        #pragma unroll
        for (int r = 0; r < 4; ++r) dv[r] = dinv[node0 + q * 4 + r];
        #pragma unroll
        for (int c2 = 0; c2 < 2; ++c2) {
            int oc = (wid * 2 + c2 - 4) * 16 + nl;
            float bias = br[oc];
            #pragma unroll
            for (int r = 0; r < 4; ++r) {
                int node = node0 + q * 4 + r;
                float sg = fast_sigmoid(acc[c2][r] + bias);
                float rhv = sg * bfu(hb[(size_t)node * C + oc]);
                rhb[(size_t)node * C + oc] = (unsigned short)f2bf(rhv);
                rhd[(size_t)node * C + oc] = (unsigned short)f2bf(rhv * dv[r]);
            }
        }
    }
}

// ======================= K5: fused prop1 + h-GEMM + GRU blend =======================
// Same block shape. Phase A gathers Prh from rhd into LDS; phase B: wave w
// computes column tile ct = w of the 16x64 candidate, then blends.
__global__ __launch_bounds__(256) void prop_gemm_h_kernel(
        const int* __restrict__ cnt, const unsigned* __restrict__ csr,
        const float* __restrict__ dinv, const unsigned short* __restrict__ rhd,
        const unsigned short* __restrict__ xb, const unsigned short* __restrict__ rhb,
        const unsigned short* __restrict__ Pxb,
        const short* __restrict__ Bh, const float* __restrict__ bh,
        const float* __restrict__ z, const float* __restrict__ h,
        float* __restrict__ out) {
    __shared__ __align__(16) unsigned short lpr[16][72];
    int tid = threadIdx.x;
    int wid = tid >> 6, lane = tid & 63;
    int node0 = blockIdx.x * 16;

    // ---- phase A: gather 4 nodes per wave ----
    #pragma unroll
    for (int i = 0; i < 4; ++i) {
        int nl = wid * 4 + i;
        int n = node0 + nl;
        int m = min(cnt[n], SLOTS);
        const unsigned* s = csr + (size_t)n * SLOTS;
        float acc = 0.f;
        int e = 0;
        for (; e + 4 <= m; e += 4) {
            unsigned p0 = s[e], p1 = s[e + 1], p2 = s[e + 2], p3 = s[e + 3];
            float v0 = bfu(rhd[(p0 >> 16) * C + lane]);
            float v1 = bfu(rhd[(p1 >> 16) * C + lane]);
            float v2 = bfu(rhd[(p2 >> 16) * C + lane]);
            float v3 = bfu(rhd[(p3 >> 16) * C + lane]);
            acc = fmaf(bf_lo(p0), v0, acc);
            acc = fmaf(bf_lo(p1), v1, acc);
            acc = fmaf(bf_lo(p2), v2, acc);
            acc = fmaf(bf_lo(p3), v3, acc);
        }
        for (; e < m; ++e) {
            unsigned p = s[e];
            acc = fmaf(bf_lo(p), bfu(rhd[(p >> 16) * C + lane]), acc);
        }
        lpr[nl][lane] = (unsigned short)f2bf(-dinv[n] * acc);
    }
    __syncthreads();

    // ---- phase B: 16 nodes x 16 cols per wave (ct = wid) ----
    int q = lane >> 4;
    int nl = lane & 15;
    f32x4 acc = (f32x4){0.f, 0.f, 0.f, 0.f};
    const bf16x8* Bp = (const bf16x8*)Bh;
    #pragma unroll
    for (int kt = 0; kt < 8; ++kt) {
        bf16x8 a;
        if (kt < 6) {
            const unsigned short* src = (kt < 2) ? xb : (kt < 4) ? rhb : Pxb;
            a = *(const bf16x8*)(src + (size_t)(node0 + nl) * C + (kt & 1) * 32 + q * 8);
        } else {
            a = *(const bf16x8*)(&lpr[0][0] + nl * 72 + (kt & 1) * 32 + q * 8);
        }
        bf16x8 bfr = Bp[(kt * 4 + wid) * 64 + lane];
        acc = __builtin_amdgcn_mfma_f32_16x16x32_bf16(a, bfr, acc, 0, 0, 0);
    }

    int oc = wid * 16 + nl;
    float bias = bh[oc];
    #pragma unroll
    for (int r = 0; r < 4; ++r) {
        int node = node0 + q * 4 + r;
        float ht = fast_tanh(acc[r] + bias);
        float zz = z[(size_t)node * C + oc];
        float hv = h[(size_t)node * C + oc];   // fp32 h for final blend accuracy
        out[(size_t)node * C + oc] = (1.f - zz) * hv + zz * ht;
    }
}

extern "C" void kernel_launch(void* const* d_in, const int* in_sizes, int n_in,
                              void* d_out, int out_size, void* d_ws, size_t ws_size,
                              hipStream_t stream) {
    const float* x    = (const float*)d_in[0];
    const int*   eidx = (const int*)  d_in[1];
    const float* w    = (const float*)d_in[2];
    const float* h    = (const float*)d_in[3];
    const float* Wz   = (const float*)d_in[4];
    const float* bz   = (const float*)d_in[5];
    const float* Wr   = (const float*)d_in[6];
    const float* br   = (const float*)d_in[7];
    const float* Wh   = (const float*)d_in[8];
    const float* bh   = (const float*)d_in[9];
    float* out = (float*)d_out;
    float* ws  = (float*)d_ws;

    const int* row = eidx;
    const int* col = eidx + N_EDGES;

    int*            gcur = (int*)(ws + OFF_GCUR);
    float*          dinv = ws + OFF_DINV;
    int*            cnt  = (int*)(ws + OFF_CNT);
    unsigned*       csr  = (unsigned*)(ws + OFF_CSR);
    short*          Bzr  = (short*)(ws + OFF_BZR);
    short*          Bh   = (short*)(ws + OFF_BH);
    unsigned*       xh   = (unsigned*)(ws + OFF_XH);
    unsigned short* xb   = (unsigned short*)(ws + OFF_XB);
    unsigned short* hb   = (unsigned short*)(ws + OFF_HB);
    unsigned short* Pxb  = (unsigned short*)(ws + OFF_PXB);
    unsigned short* rhb  = (unsigned short*)(ws + OFF_RHB);
    unsigned short* rhd  = (unsigned short*)(ws + OFF_RHD);
    uint2*          stg  = (uint2*)(ws + OFF_STG);            // aliases Pxb region
    float*          z    = out;                  // z lives in d_out until gemm_h

    // K1: pack weights + zero gcur
    zero_pack_kernel<<<25, 256, 0, stream>>>(gcur, Wz, Wr, Wh, Bzr, Bh);

    // K2: stage edges into coarse buckets (coalesced run-writes)
    stage_kernel<<<STG_BLOCKS, 512, 0, stream>>>(row, col, w, gcur, stg);

    // K3: bucket-sort -> slot-CSR + cnt/dinv + xh/xb/hb
    sort_kernel<<<NB, 256, 0, stream>>>(gcur, stg, x, h, csr, cnt, dinv, xh, xb, hb);

    // K4: fused Lhat@[x|h] gather + zr GEMM (writes Pxb, z, rhb, rhd; stg dead now)
    prop_gemm_zr_kernel<<<N_NODES / 16, 256, 0, stream>>>(
        cnt, csr, dinv, xh, xb, hb, Bzr, bz, br, Pxb, z, rhb, rhd);

    // K5: fused Lhat@(r*h) gather + candidate GEMM + GRU blend
    prop_gemm_h_kernel<<<N_NODES / 16, 256, 0, stream>>>(
        cnt, csr, dinv, rhd, xb, rhb, Pxb, Bh, bh, z, h, out);
}

// Round 2
// 209.860 us; speedup vs baseline: 1.0901x; 1.0901x over previous
//
#include <hip/hip_runtime.h>
#include <cstdint>

#define N_NODES 50000
#define N_EDGES 800000
#define C 64
#define SLOTS 64                    // fixed CSR slots/node (deg~Bin: mean 16, max ~40)
#define B_N 120                     // nodes per coarse bucket
#define NB 417                      // ceil(N/B_N)
#define PCAP 2560                   // staging cap/bucket (mean 1918, ~14 sigma)
#define STG_BLOCKS 126
#define STG_CHUNK 6350              // 126*6350 >= E

typedef __attribute__((ext_vector_type(8))) short bf16x8;   // 8 bf16 in 4 VGPRs
typedef __attribute__((ext_vector_type(4))) float f32x4;

// ---------------- workspace layout (word units) ----------------
// Round-13: gather restructured for MLP (pair-interleaved, 8-wide groups,
// zero-padded csr tails). Layout unchanged from round-12.
static constexpr size_t OFF_GCUR = 0;                                // 512 ints
static constexpr size_t OFF_DINV = 512;                              // 50176 fl
static constexpr size_t OFF_CNT  = 50688;                            // 50176 ints
static constexpr size_t OFF_BZR  = 100864;                           // 16384 fl
static constexpr size_t OFF_BH   = 117248;                           // 8192 fl
static constexpr size_t OFF_CSR  = 125440;                           // N*64 uints = 3.2M
static constexpr size_t OFF_XH   = OFF_CSR + (size_t)N_NODES * 64;   // N*C uints
static constexpr size_t OFF_XB   = OFF_XH + (size_t)N_NODES * C;     // N*C ushort
static constexpr size_t OFF_HB   = OFF_XB + (size_t)N_NODES * C / 2;
static constexpr size_t OFF_PXB  = OFF_HB + (size_t)N_NODES * C / 2;
static constexpr size_t OFF_PHB  = OFF_PXB + (size_t)N_NODES * C / 2; // dead (stg alias only)
static constexpr size_t OFF_RHB  = OFF_PHB + (size_t)N_NODES * C / 2;
static constexpr size_t OFF_RHD  = OFF_RHB + (size_t)N_NODES * C / 2;
// stg aliases PXB..: needs 2*NB*PCAP = 2,135,040 words < 4*1.6M available there.
static constexpr size_t OFF_STG  = OFF_PXB;          // uint2; byte off %8==0
// end = OFF_RHD + N*C/2 = 16,125,440 words = 64.5 MB (<= 67.4 MB proven in r0)

__device__ __forceinline__ short f2bf(float f) {             // RNE fp32 -> bf16
    unsigned u = __float_as_uint(f);
    u += 0x7fffu + ((u >> 16) & 1u);
    return (short)(u >> 16);
}
__device__ __forceinline__ float bf_lo(unsigned v) { return __uint_as_float(v << 16); }
__device__ __forceinline__ float bf_hi(unsigned v) { return __uint_as_float(v & 0xffff0000u); }
__device__ __forceinline__ float bfu(unsigned short v) { return __uint_as_float((unsigned)v << 16); }
__device__ __forceinline__ float fast_sigmoid(float v) { return 1.f / (1.f + __expf(-v)); }
__device__ __forceinline__ float fast_tanh(float v) { return 1.f - 2.f / (__expf(2.f * v) + 1.f); }

// ======================= K1: zero gcur + weight pack =======================
__global__ __launch_bounds__(256) void zero_pack_kernel(
        int* __restrict__ gcur,
        const float* __restrict__ Wz, const float* __restrict__ Wr,
        const float* __restrict__ Wh,
        short* __restrict__ Bzr, short* __restrict__ Bh) {
    if (blockIdx.x == 24) {
        gcur[threadIdx.x] = 0;
        gcur[256 + threadIdx.x] = 0;
        return;
    }
    int gid = blockIdx.x * 256 + threadIdx.x;           // < 6144
    if (gid < 4096) {                                   // zr: 64 (kt,ct) x 64 lanes
        int ktct = gid >> 6, lane = gid & 63;
        int kt = ktct >> 3, ct = ktct & 7;
        int colg = ct * 16 + (lane & 15);
        int k0 = kt * 32 + (lane >> 4) * 8;
        const float* W = (colg < 64) ? Wz : Wr;
        int c = colg & 63;
        short v[8];
        #pragma unroll
        for (int j = 0; j < 8; ++j) {
            int k = k0 + j;
            v[j] = f2bf(W[(k >> 7) * (128 * 64) + (k & 127) * 64 + c]);
        }
        *(bf16x8*)(Bzr + (size_t)ktct * 512 + lane * 8) = *(bf16x8*)v;
    } else {                                            // h: 32 (kt,ct) x 64 lanes
        int idx = gid - 4096;
        int ktct = idx >> 6, lane = idx & 63;
        int kt = ktct >> 2, ct = ktct & 3;
        int colg = ct * 16 + (lane & 15);
        int k0 = kt * 32 + (lane >> 4) * 8;
        short v[8];
        #pragma unroll
        for (int j = 0; j < 8; ++j) {
            int k = k0 + j;
            v[j] = f2bf(Wh[(k >> 7) * (128 * 64) + (k & 127) * 64 + colg]);
        }
        *(bf16x8*)(Bh + (size_t)ktct * 512 + lane * 8) = *(bf16x8*)v;
    }
}

// ======================= K2: stage edges into coarse buckets =======================
__global__ __launch_bounds__(512) void stage_kernel(
        const int* __restrict__ row, const int* __restrict__ col,
        const float* __restrict__ w,
        int* __restrict__ gcur, uint2* __restrict__ stg) {
    __shared__ int lcnt[NB];
    __shared__ int lbase[NB];
    int tid = threadIdx.x;
    int e0 = blockIdx.x * STG_CHUNK;
    int e1 = min(e0 + STG_CHUNK, N_EDGES);
    for (int i = tid; i < NB; i += 512) lcnt[i] = 0;
    __syncthreads();
    for (int e = e0 + tid; e < e1; e += 512)
        atomicAdd(&lcnt[row[e] / B_N], 1);
    __syncthreads();
    for (int i = tid; i < NB; i += 512) {
        int c = lcnt[i];
        lbase[i] = c ? atomicAdd(&gcur[i], c) : 0;
        lcnt[i] = 0;
    }
    __syncthreads();
    for (int e = e0 + tid; e < e1; e += 512) {
        int r = row[e];
        int b = r / B_N;
        int off = atomicAdd(&lcnt[b], 1);
        int pos = lbase[b] + off;
        unsigned cw = ((unsigned)col[e] << 16) | (unsigned short)f2bf(w[e]);
        if (pos < PCAP)
            stg[(size_t)b * PCAP + pos] = make_uint2((unsigned)(r - b * B_N), cw);
    }
}

// ======================= K3: bucket-sort -> slot-CSR + cnt/dinv + feature pack =====
__global__ __launch_bounds__(256) void sort_kernel(
        const int* __restrict__ gcur, const uint2* __restrict__ stg,
        const float* __restrict__ x, const float* __restrict__ h,
        unsigned* __restrict__ csr, int* __restrict__ cnt, float* __restrict__ dinv,
        unsigned* __restrict__ xh,
        unsigned short* __restrict__ xb, unsigned short* __restrict__ hb) {
    __shared__ int lcnt[B_N];
    __shared__ int lbase[B_N];
    __shared__ float ldeg[B_N];
    __shared__ float ldv[B_N];
    __shared__ int scanb[128];
    __shared__ unsigned lbuf[PCAP];
    __shared__ unsigned char lnode[PCAP];
    int b = blockIdx.x, tid = threadIdx.x;
    int n0 = b * B_N;
    int m = min(gcur[b], PCAP);
    for (int i = tid; i < B_N; i += 256) { lcnt[i] = 0; ldeg[i] = 0.f; }
    __syncthreads();
    const uint2* s = stg + (size_t)b * PCAP;
    for (int i = tid; i < m; i += 256) {             // pass 1: per-node count + deg
        uint2 e = s[i];
        atomicAdd(&lcnt[e.x], 1);
        atomicAdd(&ldeg[e.x], bf_lo(e.y));
    }
    __syncthreads();
    if (tid < 128) scanb[tid] = (tid < B_N) ? lcnt[tid] : 0;   // inclusive scan (128)
    __syncthreads();
    for (int d = 1; d < 128; d <<= 1) {
        int v = 0;
        if (tid < 128 && tid >= d) v = scanb[tid - d];
        __syncthreads();
        if (tid < 128) scanb[tid] += v;
        __syncthreads();
    }
    if (tid < B_N) { lbase[tid] = scanb[tid] - lcnt[tid]; lcnt[tid] = 0; }
    __syncthreads();
    for (int i = tid; i < m; i += 256) {             // pass 2: LDS scatter (sorted)
        uint2 e = s[i];
        int off = atomicAdd(&lcnt[e.x], 1);
        int p = lbase[e.x] + off;
        lbuf[p] = e.y;
        lnode[p] = (unsigned char)e.x;
    }
    __syncthreads();
    for (int i = tid; i < m; i += 256) {             // stream out, coalesced per node
        int nl = lnode[i];
        int pos = i - lbase[nl];
        csr[(size_t)(n0 + nl) * SLOTS + pos] = lbuf[i];
    }
    // zero-fill csr tails to a multiple of 8 slots (enables uniform 8-wide
    // gather groups; zero word = col 0, weight +0.0 -> exact no-op in fmaf)
    for (int i = tid; i < B_N * 8; i += 256) {
        int nl = i >> 3;
        int node = n0 + nl;
        if (node >= N_NODES) continue;
        int mm = min(lcnt[nl], SLOTS);
        int pe = (mm + 7) & ~7;
        int idx = mm + (i & 7);
        if (idx < pe) csr[(size_t)node * SLOTS + idx] = 0u;
    }
    if (tid < B_N) {                                  // cnt + dinv
        int node = n0 + tid;
        if (node < N_NODES) {
            cnt[node] = lcnt[tid];
            float d = ldeg[tid];
            float dv = (d > 0.f) ? rsqrtf(d) : 0.f;
            dinv[node] = dv;
            ldv[tid] = dv;
        } else ldv[tid] = 0.f;
    }
    __syncthreads();
    for (int i = tid; i < B_N * 16; i += 256) {       // feature pack (float4 groups)
        int g = n0 * 16 + i;
        if (g >= N_NODES * 16) continue;
        float dv = ldv[i >> 4];
        float4 xv = ((const float4*)x)[g];
        float4 hv = ((const float4*)h)[g];
        uint4 o;
        o.x = ((unsigned)(unsigned short)f2bf(hv.x * dv) << 16) | (unsigned short)f2bf(xv.x * dv);
        o.y = ((unsigned)(unsigned short)f2bf(hv.y * dv) << 16) | (unsigned short)f2bf(xv.y * dv);
        o.z = ((unsigned)(unsigned short)f2bf(hv.z * dv) << 16) | (unsigned short)f2bf(xv.z * dv);
        o.w = ((unsigned)(unsigned short)f2bf(hv.w * dv) << 16) | (unsigned short)f2bf(xv.w * dv);
        ((uint4*)xh)[g] = o;
        ((short4*)xb)[g] = make_short4(f2bf(xv.x), f2bf(xv.y), f2bf(xv.z), f2bf(xv.w));
        ((short4*)hb)[g] = make_short4(f2bf(hv.x), f2bf(hv.y), f2bf(hv.z), f2bf(hv.w));
    }
}

// ======================= K4: fused prop2 + zr-GEMM =======================
// Block = 256 thr = 4 waves = 16 nodes. Phase A: wave w gathers nodes w*4..w*4+3
// as two PAIRS; per pair the edge loop runs 8-wide groups with sectioned
// issue (csrA|csrB|xhA|xhB|fmaA|fmaB) -> up to ~20 loads in flight, two
// serialized latencies per 16 edges (vs per 4 before). csr tails are
// zero-padded to 8, so there is no scalar tail loop.
__global__ __launch_bounds__(256) void prop_gemm_zr_kernel(
        const int* __restrict__ cnt, const unsigned* __restrict__ csr,
        const float* __restrict__ dinv, const unsigned* __restrict__ xh,
        const unsigned short* __restrict__ xb, const unsigned short* __restrict__ hb,
        const short* __restrict__ Bzr,
        const float* __restrict__ bz, const float* __restrict__ br,
        unsigned short* __restrict__ Pxb,
        float* __restrict__ z, unsigned short* __restrict__ rhb,
        unsigned short* __restrict__ rhd) {
    __shared__ __align__(16) unsigned short lpx[16][72];
    __shared__ __align__(16) unsigned short lph[16][72];
    int tid = threadIdx.x;
    int wid = tid >> 6, lane = tid & 63;
    int node0 = blockIdx.x * 16;                      // 3125 blocks, exact

    // ---- phase A: gather 4 nodes per wave, pair-interleaved ----
    #pragma unroll
    for (int i = 0; i < 2; ++i) {
        int nlA = wid * 4 + i * 2;
        int nA = node0 + nlA;
        int2 cc = *(const int2*)(cnt + nA);           // nA even -> 8B aligned
        int gqA = (min(cc.x, SLOTS) + 7) >> 3;
        int gqB = (min(cc.y, SLOTS) + 7) >> 3;
        const uint4* sA = (const uint4*)(csr + (size_t)nA * SLOTS);
        const uint4* sB = (const uint4*)(csr + (size_t)(nA + 1) * SLOTS);
        float axA = 0.f, ahA = 0.f, axB = 0.f, ahB = 0.f;
        int gmax = max(gqA, gqB);
        for (int g = 0; g < gmax; ++g) {
            bool doA = g < gqA, doB = g < gqB;        // wave-uniform branches
            uint4 a0, a1, b0, b1;
            unsigned va0, va1, va2, va3, va4, va5, va6, va7;
            unsigned vb0, vb1, vb2, vb3, vb4, vb5, vb6, vb7;
            if (doA) { a0 = sA[2 * g]; a1 = sA[2 * g + 1]; }
            if (doB) { b0 = sB[2 * g]; b1 = sB[2 * g + 1]; }
            if (doA) {
                va0 = xh[(a0.x >> 16) * C + lane];
                va1 = xh[(a0.y >> 16) * C + lane];
                va2 = xh[(a0.z >> 16) * C + lane];
                va3 = xh[(a0.w >> 16) * C + lane];
                va4 = xh[(a1.x >> 16) * C + lane];
                va5 = xh[(a1.y >> 16) * C + lane];
                va6 = xh[(a1.z >> 16) * C + lane];
                va7 = xh[(a1.w >> 16) * C + lane];
            }
            if (doB) {
                vb0 = xh[(b0.x >> 16) * C + lane];
                vb1 = xh[(b0.y >> 16) * C + lane];
                vb2 = xh[(b0.z >> 16) * C + lane];
                vb3 = xh[(b0.w >> 16) * C + lane];
                vb4 = xh[(b1.x >> 16) * C + lane];
                vb5 = xh[(b1.y >> 16) * C + lane];
                vb6 = xh[(b1.z >> 16) * C + lane];
                vb7 = xh[(b1.w >> 16) * C + lane];
            }
            if (doA) {
                float w0 = bf_lo(a0.x), w1 = bf_lo(a0.y), w2 = bf_lo(a0.z), w3 = bf_lo(a0.w);
                float w4 = bf_lo(a1.x), w5 = bf_lo(a1.y), w6 = bf_lo(a1.z), w7 = bf_lo(a1.w);
                axA = fmaf(w0, bf_lo(va0), axA);  ahA = fmaf(w0, bf_hi(va0), ahA);
                axA = fmaf(w1, bf_lo(va1), axA);  ahA = fmaf(w1, bf_hi(va1), ahA);
                axA = fmaf(w2, bf_lo(va2), axA);  ahA = fmaf(w2, bf_hi(va2), ahA);
                axA = fmaf(w3, bf_lo(va3), axA);  ahA = fmaf(w3, bf_hi(va3), ahA);
                axA = fmaf(w4, bf_lo(va4), axA);  ahA = fmaf(w4, bf_hi(va4), ahA);
                axA = fmaf(w5, bf_lo(va5), axA);  ahA = fmaf(w5, bf_hi(va5), ahA);
                axA = fmaf(w6, bf_lo(va6), axA);  ahA = fmaf(w6, bf_hi(va6), ahA);
                axA = fmaf(w7, bf_lo(va7), axA);  ahA = fmaf(w7, bf_hi(va7), ahA);
            }
            if (doB) {
                float w0 = bf_lo(b0.x), w1 = bf_lo(b0.y), w2 = bf_lo(b0.z), w3 = bf_lo(b0.w);
                float w4 = bf_lo(b1.x), w5 = bf_lo(b1.y), w6 = bf_lo(b1.z), w7 = bf_lo(b1.w);
                axB = fmaf(w0, bf_lo(vb0), axB);  ahB = fmaf(w0, bf_hi(vb0), ahB);
                axB = fmaf(w1, bf_lo(vb1), axB);  ahB = fmaf(w1, bf_hi(vb1), ahB);
                axB = fmaf(w2, bf_lo(vb2), axB);  ahB = fmaf(w2, bf_hi(vb2), ahB);
                axB = fmaf(w3, bf_lo(vb3), axB);  ahB = fmaf(w3, bf_hi(vb3), ahB);
                axB = fmaf(w4, bf_lo(vb4), axB);  ahB = fmaf(w4, bf_hi(vb4), ahB);
                axB = fmaf(w5, bf_lo(vb5), axB);  ahB = fmaf(w5, bf_hi(vb5), ahB);
                axB = fmaf(w6, bf_lo(vb6), axB);  ahB = fmaf(w6, bf_hi(vb6), ahB);
                axB = fmaf(w7, bf_lo(vb7), axB);  ahB = fmaf(w7, bf_hi(vb7), ahB);
            }
        }
        float2 dv = *(const float2*)(dinv + nA);
        unsigned short pxA = (unsigned short)f2bf(-dv.x * axA);
        unsigned short phA = (unsigned short)f2bf(-dv.x * ahA);
        unsigned short pxB = (unsigned short)f2bf(-dv.y * axB);
        unsigned short phB = (unsigned short)f2bf(-dv.y * ahB);
        lpx[nlA][lane] = pxA;      lph[nlA][lane] = phA;
        lpx[nlA + 1][lane] = pxB;  lph[nlA + 1][lane] = phB;
        Pxb[(size_t)nA * C + lane] = pxA;             // still needed by gemm_h
        Pxb[(size_t)(nA + 1) * C + lane] = pxB;
    }
    __syncthreads();

    // ---- phase B: 16 nodes x 32 cols per wave ----
    int q = lane >> 4;
    int nl = lane & 15;
    f32x4 acc[2];
    acc[0] = (f32x4){0.f, 0.f, 0.f, 0.f};
    acc[1] = (f32x4){0.f, 0.f, 0.f, 0.f};
    const bf16x8* Bp = (const bf16x8*)Bzr;
    #pragma unroll
    for (int kt = 0; kt < 8; ++kt) {
        bf16x8 a;
        if (kt < 4) {
            const unsigned short* src = (kt < 2) ? xb : hb;
            a = *(const bf16x8*)(src + (size_t)(node0 + nl) * C + (kt & 1) * 32 + q * 8);
        } else {
            const unsigned short* src = (kt < 6) ? &lpx[0][0] : &lph[0][0];
            a = *(const bf16x8*)(src + nl * 72 + (kt & 1) * 32 + q * 8);
        }
        #pragma unroll
        for (int c2 = 0; c2 < 2; ++c2) {
            int ct = wid * 2 + c2;
            bf16x8 bfr = Bp[(kt * 8 + ct) * 64 + lane];
            acc[c2] = __builtin_amdgcn_mfma_f32_16x16x32_bf16(a, bfr, acc[c2], 0, 0, 0);
        }
    }

    if (wid < 2) {                                    // z columns (ct 0..3)
        #pragma unroll
        for (int c2 = 0; c2 < 2; ++c2) {
            int colg = (wid * 2 + c2) * 16 + nl;
            float bias = bz[colg];
            #pragma unroll
            for (int r = 0; r < 4; ++r) {
                int node = node0 + q * 4 + r;
                z[(size_t)node * C + colg] = fast_sigmoid(acc[c2][r] + bias);
            }
        }
    } else {                                          // r columns (ct 4..7)
        float dv[4];
        #pragma unroll
        for (int r = 0; r < 4; ++r) dv[r] = dinv[node0 + q * 4 + r];
        #pragma unroll
        for (int c2 = 0; c2 < 2; ++c2) {
            int oc = (wid * 2 + c2 - 4) * 16 + nl;
            float bias = br[oc];
            #pragma unroll
            for (int r = 0; r < 4; ++r) {
                int node = node0 + q * 4 + r;
                float sg = fast_sigmoid(acc[c2][r] + bias);
                float rhv = sg * bfu(hb[(size_t)node * C + oc]);
                rhb[(size_t)node * C + oc] = (unsigned short)f2bf(rhv);
                rhd[(size_t)node * C + oc] = (unsigned short)f2bf(rhv * dv[r]);
            }
        }
    }
}

// ======================= K5: fused prop1 + h-GEMM + GRU blend =======================
// Same pair-interleaved 8-wide gather, values from rhd (ushort).
__global__ __launch_bounds__(256) void prop_gemm_h_kernel(
        const int* __restrict__ cnt, const unsigned* __restrict__ csr,
        const float* __restrict__ dinv, const unsigned short* __restrict__ rhd,
        const unsigned short* __restrict__ xb, const unsigned short* __restrict__ rhb,
        const unsigned short* __restrict__ Pxb,
        const short* __restrict__ Bh, const float* __restrict__ bh,
        const float* __restrict__ z, const float* __restrict__ h,
        float* __restrict__ out) {
    __shared__ __align__(16) unsigned short lpr[16][72];
    int tid = threadIdx.x;
    int wid = tid >> 6, lane = tid & 63;
    int node0 = blockIdx.x * 16;

    // ---- phase A: gather 4 nodes per wave, pair-interleaved ----
    #pragma unroll
    for (int i = 0; i < 2; ++i) {
        int nlA = wid * 4 + i * 2;
        int nA = node0 + nlA;
        int2 cc = *(const int2*)(cnt + nA);
        int gqA = (min(cc.x, SLOTS) + 7) >> 3;
        int gqB = (min(cc.y, SLOTS) + 7) >> 3;
        const uint4* sA = (const uint4*)(csr + (size_t)nA * SLOTS);
        const uint4* sB = (const uint4*)(csr + (size_t)(nA + 1) * SLOTS);
        float accA = 0.f, accB = 0.f;
        int gmax = max(gqA, gqB);
        for (int g = 0; g < gmax; ++g) {
            bool doA = g < gqA, doB = g < gqB;
            uint4 a0, a1, b0, b1;
            unsigned short va0, va1, va2, va3, va4, va5, va6, va7;
            unsigned short vb0, vb1, vb2, vb3, vb4, vb5, vb6, vb7;
            if (doA) { a0 = sA[2 * g]; a1 = sA[2 * g + 1]; }
            if (doB) { b0 = sB[2 * g]; b1 = sB[2 * g + 1]; }
            if (doA) {
                va0 = rhd[(a0.x >> 16) * C + lane];
                va1 = rhd[(a0.y >> 16) * C + lane];
                va2 = rhd[(a0.z >> 16) * C + lane];
                va3 = rhd[(a0.w >> 16) * C + lane];
                va4 = rhd[(a1.x >> 16) * C + lane];
                va5 = rhd[(a1.y >> 16) * C + lane];
                va6 = rhd[(a1.z >> 16) * C + lane];
                va7 = rhd[(a1.w >> 16) * C + lane];
            }
            if (doB) {
                vb0 = rhd[(b0.x >> 16) * C + lane];
                vb1 = rhd[(b0.y >> 16) * C + lane];
                vb2 = rhd[(b0.z >> 16) * C + lane];
                vb3 = rhd[(b0.w >> 16) * C + lane];
                vb4 = rhd[(b1.x >> 16) * C + lane];
                vb5 = rhd[(b1.y >> 16) * C + lane];
                vb6 = rhd[(b1.z >> 16) * C + lane];
                vb7 = rhd[(b1.w >> 16) * C + lane];
            }
            if (doA) {
                accA = fmaf(bf_lo(a0.x), bfu(va0), accA);
                accA = fmaf(bf_lo(a0.y), bfu(va1), accA);
                accA = fmaf(bf_lo(a0.z), bfu(va2), accA);
                accA = fmaf(bf_lo(a0.w), bfu(va3), accA);
                accA = fmaf(bf_lo(a1.x), bfu(va4), accA);
                accA = fmaf(bf_lo(a1.y), bfu(va5), accA);
                accA = fmaf(bf_lo(a1.z), bfu(va6), accA);
                accA = fmaf(bf_lo(a1.w), bfu(va7), accA);
            }
            if (doB) {
                accB = fmaf(bf_lo(b0.x), bfu(vb0), accB);
                accB = fmaf(bf_lo(b0.y), bfu(vb1), accB);
                accB = fmaf(bf_lo(b0.z), bfu(vb2), accB);
                accB = fmaf(bf_lo(b0.w), bfu(vb3), accB);
                accB = fmaf(bf_lo(b1.x), bfu(vb4), accB);
                accB = fmaf(bf_lo(b1.y), bfu(vb5), accB);
                accB = fmaf(bf_lo(b1.z), bfu(vb6), accB);
                accB = fmaf(bf_lo(b1.w), bfu(vb7), accB);
            }
        }
        float2 dv = *(const float2*)(dinv + nA);
        lpr[nlA][lane]     = (unsigned short)f2bf(-dv.x * accA);
        lpr[nlA + 1][lane] = (unsigned short)f2bf(-dv.y * accB);
    }
    __syncthreads();

    // ---- phase B: 16 nodes x 16 cols per wave (ct = wid) ----
    int q = lane >> 4;
    int nl = lane & 15;
    f32x4 acc = (f32x4){0.f, 0.f, 0.f, 0.f};
    const bf16x8* Bp = (const bf16x8*)Bh;
    #pragma unroll
    for (int kt = 0; kt < 8; ++kt) {
        bf16x8 a;
        if (kt < 6) {
            const unsigned short* src = (kt < 2) ? xb : (kt < 4) ? rhb : Pxb;
            a = *(const bf16x8*)(src + (size_t)(node0 + nl) * C + (kt & 1) * 32 + q * 8);
        } else {
            a = *(const bf16x8*)(&lpr[0][0] + nl * 72 + (kt & 1) * 32 + q * 8);
        }
        bf16x8 bfr = Bp[(kt * 4 + wid) * 64 + lane];
        acc = __builtin_amdgcn_mfma_f32_16x16x32_bf16(a, bfr, acc, 0, 0, 0);
    }

    int oc = wid * 16 + nl;
    float bias = bh[oc];
    #pragma unroll
    for (int r = 0; r < 4; ++r) {
        int node = node0 + q * 4 + r;
        float ht = fast_tanh(acc[r] + bias);
        float zz = z[(size_t)node * C + oc];
        float hv = h[(size_t)node * C + oc];   // fp32 h for final blend accuracy
        out[(size_t)node * C + oc] = (1.f - zz) * hv + zz * ht;
    }
}

extern "C" void kernel_launch(void* const* d_in, const int* in_sizes, int n_in,
                              void* d_out, int out_size, void* d_ws, size_t ws_size,
                              hipStream_t stream) {
    const float* x    = (const float*)d_in[0];
    const int*   eidx = (const int*)  d_in[1];
    const float* w    = (const float*)d_in[2];
    const float* h    = (const float*)d_in[3];
    const float* Wz   = (const float*)d_in[4];
    const float* bz   = (const float*)d_in[5];
    const float* Wr   = (const float*)d_in[6];
    const float* br   = (const float*)d_in[7];
    const float* Wh   = (const float*)d_in[8];
    const float* bh   = (const float*)d_in[9];
    float* out = (float*)d_out;
    float* ws  = (float*)d_ws;

    const int* row = eidx;
    const int* col = eidx + N_EDGES;

    int*            gcur = (int*)(ws + OFF_GCUR);
    float*          dinv = ws + OFF_DINV;
    int*            cnt  = (int*)(ws + OFF_CNT);
    unsigned*       csr  = (unsigned*)(ws + OFF_CSR);
    short*          Bzr  = (short*)(ws + OFF_BZR);
    short*          Bh   = (short*)(ws + OFF_BH);
    unsigned*       xh   = (unsigned*)(ws + OFF_XH);
    unsigned short* xb   = (unsigned short*)(ws + OFF_XB);
    unsigned short* hb   = (unsigned short*)(ws + OFF_HB);
    unsigned short* Pxb  = (unsigned short*)(ws + OFF_PXB);
    unsigned short* rhb  = (unsigned short*)(ws + OFF_RHB);
    unsigned short* rhd  = (unsigned short*)(ws + OFF_RHD);
    uint2*          stg  = (uint2*)(ws + OFF_STG);            // aliases Pxb region
    float*          z    = out;                  // z lives in d_out until gemm_h

    // K1: pack weights + zero gcur
    zero_pack_kernel<<<25, 256, 0, stream>>>(gcur, Wz, Wr, Wh, Bzr, Bh);

    // K2: stage edges into coarse buckets (coalesced run-writes)
    stage_kernel<<<STG_BLOCKS, 512, 0, stream>>>(row, col, w, gcur, stg);

    // K3: bucket-sort -> slot-CSR + cnt/dinv + xh/xb/hb (csr tails zero-padded)
    sort_kernel<<<NB, 256, 0, stream>>>(gcur, stg, x, h, csr, cnt, dinv, xh, xb, hb);

    // K4: fused Lhat@[x|h] gather + zr GEMM (writes Pxb, z, rhb, rhd; stg dead now)
    prop_gemm_zr_kernel<<<N_NODES / 16, 256, 0, stream>>>(
        cnt, csr, dinv, xh, xb, hb, Bzr, bz, br, Pxb, z, rhb, rhd);

    // K5: fused Lhat@(r*h) gather + candidate GEMM + GRU blend
    prop_gemm_h_kernel<<<N_NODES / 16, 256, 0, stream>>>(
        cnt, csr, dinv, rhd, xb, rhb, Pxb, Bh, bh, z, h, out);
}